// Round 6
// baseline (329.112 us; speedup 1.0000x reference)
//
#include <hip/hip_runtime.h>

// ChamferDistance: B=4, N=M=8192, fp32 3-D points.
// R6: two-orientation 32x32x16 bf16 MFMA (layout verified R5, absmax 0.0156)
//   A-form(p): [-2ph(3), -2pl(3), -2ph(3), nh, nl, 1, 1, 0,0,0]  (K=16)
//   B-form(p): [  ph(3),   ph(3),   pl(3),  1,  1, nh, nl, 0,0,0]
// New this round:
//  - B staged per BLOCK in double-buffered LDS via global_load_lds(16B):
//    L2 traffic 268 MB -> 67 MB (was the hidden bottleneck at ~80% L2 peak).
//  - tile-PAIR processing: rmin = min(min(accT, accT+1), rmin) -> v_min3_f32
//    halves the per-element VALU cost (the arithmetic floor).
//  - loads for stage s+1 in flight across compute of stage s (2-phase T3-lite).

typedef short  short8 __attribute__((ext_vector_type(8)));
typedef float  f32x16 __attribute__((ext_vector_type(16)));

#define B_      4
#define NPT     8192
#define THREADS 256
#define ROWBLK  32               // 256-row blocks per (pass, batch)
#define NCHUNK  4                // col chunks -> grid = 2*4*32*4 = 1024
#define CCOLS   (NPT / NCHUNK)   // 2048 cols per chunk
#define STAGE_C 256              // cols per LDS stage (8 KB)
#define NSTAGE  (CCOLS / STAGE_C)
#define PINF_I  0x7f800000

__device__ __forceinline__ unsigned short f2bf(float x) {
    unsigned u = __float_as_uint(x);
    u += 0x7fff + ((u >> 16) & 1);
    return (unsigned short)(u >> 16);
}
__device__ __forceinline__ float bf2f(unsigned short b) {
    return __uint_as_float(((unsigned)b) << 16);
}
#define PK2(a, b) ((((unsigned)(b)) << 16) | (unsigned)(a))

__device__ __forceinline__ void pack_point(const float* __restrict__ xyz, int i,
                                           unsigned short* __restrict__ Aform,
                                           unsigned short* __restrict__ Bform) {
    const unsigned short one = 0x3f80;
    float x0 = xyz[3*i], x1 = xyz[3*i+1], x2 = xyz[3*i+2];
    unsigned short h0 = f2bf(x0), h1 = f2bf(x1), h2 = f2bf(x2);
    unsigned short l0 = f2bf(x0 - bf2f(h0)), l1 = f2bf(x1 - bf2f(h1)), l2 = f2bf(x2 - bf2f(h2));
    unsigned short m0 = f2bf(-2.f * bf2f(h0)), m1 = f2bf(-2.f * bf2f(h1)), m2 = f2bf(-2.f * bf2f(h2));
    unsigned short q0 = f2bf(-2.f * bf2f(l0)), q1 = f2bf(-2.f * bf2f(l1)), q2 = f2bf(-2.f * bf2f(l2));
    float n = x0*x0 + x1*x1 + x2*x2;
    unsigned short nh = f2bf(n), nl = f2bf(n - bf2f(nh));
    uint4 a0 = make_uint4(PK2(m0, m1), PK2(m2, q0), PK2(q1, q2), PK2(m0, m1));
    uint4 a1 = make_uint4(PK2(m2, nh), PK2(nl, one), PK2(one, 0), PK2(0, 0));
    ((uint4*)Aform)[(size_t)i * 2]     = a0;
    ((uint4*)Aform)[(size_t)i * 2 + 1] = a1;
    uint4 b0 = make_uint4(PK2(h0, h1), PK2(h2, h0), PK2(h1, h2), PK2(l0, l1));
    uint4 b1 = make_uint4(PK2(l2, one), PK2(one, nh), PK2(nl, 0), PK2(0, 0));
    ((uint4*)Bform)[(size_t)i * 2]     = b0;
    ((uint4*)Bform)[(size_t)i * 2 + 1] = b1;
}

__global__ __launch_bounds__(THREADS)
void cd_pack(const float* __restrict__ xyz1, const float* __restrict__ xyz2,
             unsigned short* __restrict__ A1, unsigned short* __restrict__ B1,
             unsigned short* __restrict__ A2, unsigned short* __restrict__ B2,
             int* __restrict__ out) {
    int i = blockIdx.x * THREADS + threadIdx.x;
    if (i >= B_ * NPT) return;
    pack_point(xyz1, i, A1, B1);
    pack_point(xyz2, i, A2, B2);
    out[i] = PINF_I;
    out[(size_t)B_ * NPT + i] = PINF_I;
}

__global__ __launch_bounds__(THREADS, 4)    // cap 128 VGPR -> 4 waves/SIMD
void cd_mfma32(const unsigned short* __restrict__ A1, const unsigned short* __restrict__ B1,
               const unsigned short* __restrict__ A2, const unsigned short* __restrict__ B2,
               int* __restrict__ out) {
    __shared__ unsigned short ysh[2][STAGE_C * 16];   // 2 x 8 KB

    int bid = blockIdx.x;
    const int c    = bid & (NCHUNK - 1);  bid >>= 2;
    const int rb   = bid & (ROWBLK - 1);  bid >>= 5;
    const int b    = bid & (B_ - 1);      bid >>= 2;
    const int pass = bid;                               // 0: dist1, 1: dist2

    const unsigned short* __restrict__ Ap = pass ? A2 : A1;
    const unsigned short* __restrict__ Bp = pass ? B1 : B2;
    int* __restrict__ o = out + (size_t)pass * B_ * NPT;

    const int tid  = threadIdx.x;
    const int lane = tid & 63;
    const int w    = tid >> 6;
    const int l31  = lane & 31;
    const int kg   = lane >> 5;            // k-half: k = kg*8 + i

    const size_t bbase   = (size_t)b * NPT;
    const int    rowBase = rb * 256 + w * 64;

    // A fragments: 2 row-tiles x 32 rows, resident for the whole sweep
    short8 afrag[2];
    #pragma unroll
    for (int rt = 0; rt < 2; ++rt)
        afrag[rt] = *(const short8*)(Ap + (bbase + rowBase + rt*32 + l31) * 16 + kg * 8);

    float rmin0[16], rmin1[16];
    #pragma unroll
    for (int r = 0; r < 16; ++r) { rmin0[r] = __int_as_float(PINF_I); rmin1[r] = __int_as_float(PINF_I); }

    const unsigned short* gB = Bp + (bbase + (size_t)c * CCOLS) * 16;

    // Stage s (256 cols = 8 KB) into buffer nb: 2 x global_load_lds(16B)/thread.
    // LDS dest = wave-uniform base + lane*16 (HW rule); global matches linearly.
    auto stage = [&](int s, int nb) {
        const unsigned short* g = gB + (size_t)s * STAGE_C * 16;
        #pragma unroll
        for (int r = 0; r < 2; ++r) {
            const unsigned short* gp = g + r * 2048 + w * 512 + lane * 8;   // ushort idx
            unsigned short* lp = &ysh[nb][r * 2048 + w * 512];
            __builtin_amdgcn_global_load_lds(
                (const __attribute__((address_space(1))) unsigned int*)gp,
                (__attribute__((address_space(3))) unsigned int*)lp, 16, 0, 0);
        }
    };

    // Compute 8 tiles (4 pairs) from buffer nb. Pair form feeds v_min3_f32.
    auto compute = [&](int nb) {
        const unsigned short* bsh = &ysh[nb][0];
        #pragma unroll
        for (int p = 0; p < 4; ++p) {
            short8 b0 = *(const short8*)(bsh + (p*64 +  0 + l31) * 16 + kg * 8);
            short8 b1 = *(const short8*)(bsh + (p*64 + 32 + l31) * 16 + kg * 8);
            f32x16 z = {0.f};
            f32x16 a00 = __builtin_amdgcn_mfma_f32_32x32x16_bf16(afrag[0], b0, z, 0, 0, 0);
            f32x16 a01 = __builtin_amdgcn_mfma_f32_32x32x16_bf16(afrag[0], b1, z, 0, 0, 0);
            #pragma unroll
            for (int r = 0; r < 16; ++r)
                rmin0[r] = fminf(fminf(a00[r], a01[r]), rmin0[r]);   // v_min3_f32
            f32x16 a10 = __builtin_amdgcn_mfma_f32_32x32x16_bf16(afrag[1], b0, z, 0, 0, 0);
            f32x16 a11 = __builtin_amdgcn_mfma_f32_32x32x16_bf16(afrag[1], b1, z, 0, 0, 0);
            #pragma unroll
            for (int r = 0; r < 16; ++r)
                rmin1[r] = fminf(fminf(a10[r], a11[r]), rmin1[r]);
        }
    };

    stage(0, 0);
    asm volatile("s_waitcnt vmcnt(0)" ::: "memory");
    __syncthreads();
    for (int s = 0; s < NSTAGE; ++s) {
        if (s + 1 < NSTAGE) stage(s + 1, (s + 1) & 1);   // loads fly over compute
        compute(s & 1);
        if (s + 1 < NSTAGE) {
            asm volatile("s_waitcnt vmcnt(0)" ::: "memory");
            __syncthreads();
        }
    }

    // Epilogue: butterfly row-mins across the 32 col-slots, one atomic per row
    #pragma unroll
    for (int rt = 0; rt < 2; ++rt) {
        float* rm = rt ? rmin1 : rmin0;
        #pragma unroll
        for (int r = 0; r < 16; ++r) {
            float v = rm[r];
            v = fminf(v, __shfl_xor(v, 1, 64));
            v = fminf(v, __shfl_xor(v, 2, 64));
            v = fminf(v, __shfl_xor(v, 4, 64));
            v = fminf(v, __shfl_xor(v, 8, 64));
            v = fminf(v, __shfl_xor(v, 16, 64));
            if (l31 == 0) {
                int row = rowBase + rt*32 + (r & 3) + 8*(r >> 2) + 4*kg;
                atomicMin(&o[bbase + row], __float_as_int(fmaxf(v, 0.f)));
            }
        }
    }
}

extern "C" void kernel_launch(void* const* d_in, const int* in_sizes, int n_in,
                              void* d_out, int out_size, void* d_ws, size_t ws_size,
                              hipStream_t stream) {
    const float* xyz1 = (const float*)d_in[0];
    const float* xyz2 = (const float*)d_in[1];

    const size_t PSZ = (size_t)B_ * NPT * 16;       // ushorts per packed array
    unsigned short* A1 = (unsigned short*)d_ws;     // 4 x 1 MB in d_ws
    unsigned short* B1 = A1 + PSZ;
    unsigned short* A2 = B1 + PSZ;
    unsigned short* B2 = A2 + PSZ;

    cd_pack<<<(B_ * NPT + THREADS - 1) / THREADS, THREADS, 0, stream>>>(
        xyz1, xyz2, A1, B1, A2, B2, (int*)d_out);

    cd_mfma32<<<2 * B_ * ROWBLK * NCHUNK, THREADS, 0, stream>>>(
        A1, B1, A2, B2, (int*)d_out);
}